// Round 1
// baseline (309.943 us; speedup 1.0000x reference)
//
#include <hip/hip_runtime.h>
#include <hip/hip_bf16.h>

// SwitchLinear: B=4,S=2048,D_IN=1024,D_OUT=1024,E=8
// Established contract: ALL inputs fp32, OUTPUT fp32 (out_size=8388609 floats:
// 8192x1024 dense out + aux scalar). ws >= 262400 B. Routing = argmax of fp32
// gate logits; out[t,:] = x[t]@We[top1]^T + be[top1]; aux = mean((mean_gate*E)^2).
// Value GEMM: bf16 MFMA (input-rounding error ~1e-3 << 6.4e-2 threshold).

#define NTOK 8192
#define DIN  1024
#define DOUT 1024
#define NE   8

typedef unsigned short u16;
typedef short  bf16x8 __attribute__((ext_vector_type(8)));
typedef float  f32x4  __attribute__((ext_vector_type(4)));

__device__ __forceinline__ u16 f2bf(float f) {
    __hip_bfloat16 h = __float2bfloat16(f);   // RNE
    return *(u16*)&h;
}

// ws: [0,32) counts | [32,64) mean-gate sums | [256, 262400) per-expert token lists

// ---------------------------------------------------------------------------
// gate v2: one wave per token, 2048 blocks (8 blocks/CU -> real TLP).
// No LDS staging of Wg (32 KB, L1/L2-resident). Lane layout: 8 groups x 8
// lanes; group g computes expert g's dot product. x addresses duplicate
// across the 8 groups -> coalescer broadcasts (HBM traffic stays 1x).
// Reduce = 3 shfl_xor (within 8-lane group) + 8 broadcast shuffles.
// ---------------------------------------------------------------------------
__global__ __launch_bounds__(256) void gate_kernel(
    const float* __restrict__ x, const float* __restrict__ Wg,
    const float* __restrict__ bg, int* __restrict__ counts,
    float* __restrict__ mg_sum, int* __restrict__ tok_list)
{
    __shared__ float mg_s[NE];
    const int tid = threadIdx.x;
    if (tid < NE) mg_s[tid] = 0.f;
    __syncthreads();

    const int wave = tid >> 6;
    const int lane = tid & 63;
    const int t    = blockIdx.x * 4 + wave;     // grid = 2048 -> t in [0,8192)
    const int g    = lane >> 3;                 // expert this lane group computes
    const int sub  = lane & 7;

    const float* xr = x  + (size_t)t * DIN + 4 * sub;
    const float* wr = Wg + g * DIN + 4 * sub;

    // k = 4*sub + 128*j + {0,32,64,96} + q  covers [0,1024) exactly
    float acc0 = 0.f, acc1 = 0.f, acc2 = 0.f, acc3 = 0.f;
    #pragma unroll
    for (int j = 0; j < 8; ++j) {
        const int k = j * 128;
        f32x4 x0 = *(const f32x4*)(xr + k);
        f32x4 w0 = *(const f32x4*)(wr + k);
        f32x4 x1 = *(const f32x4*)(xr + k + 32);
        f32x4 w1 = *(const f32x4*)(wr + k + 32);
        f32x4 x2 = *(const f32x4*)(xr + k + 64);
        f32x4 w2 = *(const f32x4*)(wr + k + 64);
        f32x4 x3 = *(const f32x4*)(xr + k + 96);
        f32x4 w3 = *(const f32x4*)(wr + k + 96);
        #pragma unroll
        for (int q = 0; q < 4; ++q) {
            acc0 = fmaf(w0[q], x0[q], acc0);
            acc1 = fmaf(w1[q], x1[q], acc1);
            acc2 = fmaf(w2[q], x2[q], acc2);
            acc3 = fmaf(w3[q], x3[q], acc3);
        }
    }
    float acc = (acc0 + acc1) + (acc2 + acc3);

    // reduce across the 8 lanes of this expert group
    acc += __shfl_xor(acc, 1, 64);
    acc += __shfl_xor(acc, 2, 64);
    acc += __shfl_xor(acc, 4, 64);

    // every lane gathers all 8 expert logits
    float logit[NE];
    #pragma unroll
    for (int e = 0; e < NE; ++e)
        logit[e] = __shfl(acc, e * 8, 64) + bg[e];

    // argmax, first-max wins (matches np/jnp)
    float m = logit[0]; int am = 0;
    #pragma unroll
    for (int e = 1; e < NE; ++e) if (logit[e] > m) { m = logit[e]; am = e; }

    float p[NE], s = 0.f;
    #pragma unroll
    for (int e = 0; e < NE; ++e) { p[e] = __expf(logit[e] - m); s += p[e]; }
    const float inv = 1.f / s;

    if (lane < NE) atomicAdd(&mg_s[lane], p[lane] * inv);
    if (lane == 0) {
        int pos = atomicAdd(&counts[am], 1);
        tok_list[am * NTOK + pos] = t;
    }
    __syncthreads();
    if (tid < NE) atomicAdd(&mg_sum[tid], mg_s[tid]);
}

// ---------------------------------------------------------------------------
// grouped GEMM: per expert e, C[rows(e), 1024] = X[rows(e), :] @ We[e]^T + be[e]
// 128x128 tile, BK=32, 4 waves each 64x64 (4x4 of mfma 16x16x32 bf16).
// v2: double-buffered LDS + async-stage split (T14/T3-minimum): issue next
// K-tile's global loads BEFORE the ds_read+MFMA phase, cvt+LDS-write after,
// ONE barrier per K-step (was 2).
// ---------------------------------------------------------------------------
__global__ __launch_bounds__(256) void moe_gemm(
    const float* __restrict__ x, const float* __restrict__ We,
    const float* __restrict__ be, const int* __restrict__ counts,
    const int* __restrict__ tok_list, float* __restrict__ out)
{
    const int e   = blockIdx.z;
    const int cnt = counts[e];
    const int m0  = blockIdx.y * 128;
    if (m0 >= cnt) return;
    const int n0  = blockIdx.x * 128;

    __shared__ u16 sA[2][128 * 32];
    __shared__ u16 sB[2][128 * 32];
    __shared__ int toks[128];

    const int tid = threadIdx.x;
    if (tid < 128) {
        int gr = m0 + tid;
        toks[tid] = (gr < cnt) ? tok_list[e * NTOK + gr] : tok_list[e * NTOK];
    }
    __syncthreads();

    const int lane = tid & 63;
    const int wave = tid >> 6;
    const int wm   = (wave & 1) * 64;
    const int wn   = (wave >> 1) * 64;
    const int lrow = lane & 15;
    const int quad = lane >> 4;

    f32x4 acc[4][4];
    #pragma unroll
    for (int i = 0; i < 4; ++i)
        #pragma unroll
        for (int j = 0; j < 4; ++j) acc[i][j] = (f32x4){0.f, 0.f, 0.f, 0.f};

    const int srow  = tid >> 1;        // 0..127
    const int shalf = (tid & 1) * 16;  // 0 / 16 elems

    const float* xrow = x  + (size_t)toks[srow] * DIN + shalf;
    const float* brow = We + ((size_t)e << 20) + ((size_t)(n0 + srow) << 10) + shalf;

    f32x4 ra[4], rb[4];

    #define LOADT(k0)                                            \
        do {                                                     \
            _Pragma("unroll")                                    \
            for (int q = 0; q < 4; ++q) {                        \
                ra[q] = *(const f32x4*)(xrow + (k0) + 4 * q);    \
                rb[q] = *(const f32x4*)(brow + (k0) + 4 * q);    \
            }                                                    \
        } while (0)

    #define STORET(buf)                                          \
        do {                                                     \
            union { u16 h[16]; uint4 u[2]; } pa, pb;             \
            _Pragma("unroll")                                    \
            for (int q = 0; q < 4; ++q)                          \
                _Pragma("unroll")                                \
                for (int j = 0; j < 4; ++j) {                    \
                    pa.h[q * 4 + j] = f2bf(ra[q][j]);            \
                    pb.h[q * 4 + j] = f2bf(rb[q][j]);            \
                }                                                \
            *(uint4*)&sA[buf][srow * 32 + shalf]     = pa.u[0];  \
            *(uint4*)&sA[buf][srow * 32 + shalf + 8] = pa.u[1];  \
            *(uint4*)&sB[buf][srow * 32 + shalf]     = pb.u[0];  \
            *(uint4*)&sB[buf][srow * 32 + shalf + 8] = pb.u[1];  \
        } while (0)

    #define MFMA_TILE(buf)                                                     \
        do {                                                                   \
            bf16x8 af[4], bfr[4];                                              \
            _Pragma("unroll")                                                  \
            for (int i = 0; i < 4; ++i)                                        \
                af[i] = *(const bf16x8*)&sA[buf][(wm + i * 16 + lrow) * 32 + quad * 8]; \
            _Pragma("unroll")                                                  \
            for (int j = 0; j < 4; ++j)                                        \
                bfr[j] = *(const bf16x8*)&sB[buf][(wn + j * 16 + lrow) * 32 + quad * 8]; \
            _Pragma("unroll")                                                  \
            for (int i = 0; i < 4; ++i)                                        \
                _Pragma("unroll")                                              \
                for (int j = 0; j < 4; ++j)                                    \
                    acc[i][j] = __builtin_amdgcn_mfma_f32_16x16x32_bf16(       \
                        af[i], bfr[j], acc[i][j], 0, 0, 0);                    \
        } while (0)

    // prologue: stage K-tile 0 into buffer 0
    LOADT(0);
    STORET(0);
    __syncthreads();

    int cur = 0;
    #pragma unroll 1
    for (int k0 = 32; k0 < DIN; k0 += 32) {
        LOADT(k0);          // issue next tile's global loads (in flight during MFMA)
        MFMA_TILE(cur);     // compute on current buffer
        STORET(cur ^ 1);    // vmcnt wait happens here, after MFMA issued
        __syncthreads();    // one barrier per K-step
        cur ^= 1;
    }
    MFMA_TILE(cur);         // last tile

    // epilogue: D lane map col=lane&15 (N), row=quad*4+r (M); fp32 stores
    #pragma unroll
    for (int j = 0; j < 4; ++j) {
        const int col = n0 + wn + j * 16 + lrow;
        const float bev = be[e * DOUT + col];
        #pragma unroll
        for (int i = 0; i < 4; ++i) {
            #pragma unroll
            for (int r = 0; r < 4; ++r) {
                const int rl = wm + i * 16 + quad * 4 + r;
                if (m0 + rl < cnt) {
                    const int tok = toks[rl];
                    out[((size_t)tok << 10) + col] = acc[i][j][r] + bev;
                }
            }
        }
    }

    #undef LOADT
    #undef STORET
    #undef MFMA_TILE
}

__global__ void aux_kernel(const float* __restrict__ mg, float* __restrict__ out)
{
    if (threadIdx.x == 0) {
        float s = 0.f;
        #pragma unroll
        for (int e = 0; e < NE; ++e) {
            float m = mg[e] * (8.0f / 8192.0f);  // mean_gate * E
            s += m * m;
        }
        out[(size_t)NTOK * DOUT] = s * 0.125f;
    }
}

extern "C" void kernel_launch(void* const* d_in, const int* in_sizes, int n_in,
                              void* d_out, int out_size, void* d_ws, size_t ws_size,
                              hipStream_t stream) {
    const float* x  = (const float*)d_in[0];
    const float* We = (const float*)d_in[1];
    const float* be = (const float*)d_in[2];
    const float* Wg = (const float*)d_in[3];
    const float* bg = (const float*)d_in[4];
    float* out = (float*)d_out;

    int*   counts   = (int*)d_ws;
    float* mg       = (float*)((char*)d_ws + 32);
    int*   tok_list = (int*)((char*)d_ws + 256);

    hipMemsetAsync(d_ws, 0, 256, stream);
    gate_kernel<<<2048, 256, 0, stream>>>(x, Wg, bg, counts, mg, tok_list);
    moe_gemm<<<dim3(8, 64, 8), 256, 0, stream>>>(x, We, be, counts, tok_list, out);
    aux_kernel<<<1, 64, 0, stream>>>(mg, out);
}

// Round 2
// 186.989 us; speedup vs baseline: 1.6575x; 1.6575x over previous
//
#include <hip/hip_runtime.h>
#include <hip/hip_bf16.h>

// SwitchLinear: B=4,S=2048,D_IN=1024,D_OUT=1024,E=8
// Established contract: ALL inputs fp32, OUTPUT fp32 (out_size=8388609 floats:
// 8192x1024 dense out + aux scalar). ws >= 262400 B. Routing = argmax of fp32
// gate logits; out[t,:] = x[t]@We[top1]^T + be[top1]; aux = mean((mean_gate*E)^2).
// Value GEMM: bf16 MFMA (input-rounding error ~1e-3 << 6.4e-2 threshold).
//
// v3: ZERO global atomics in routing. gate writes per-block packed records
// (16x4bit argmax + 8 mg partials = 64B/block) into the tok_list region head;
// route_kernel (1 block) scans + scatters deterministically, writes counts,
// computes aux. Rationale: v1/v2 counters showed all pipes idle while gate
// took 100-126us -> serialized same-address device-scope atomics (~100ns ea,
// 1024-2048 per address). gemm reverted to round-0 single-buffer (dbuf cost
// ~17us: LDS 16->32KB occupancy loss, per m99/m100).

#define NTOK 8192
#define DIN  1024
#define DOUT 1024
#define NE   8

typedef unsigned short u16;
typedef unsigned int   u32;
typedef unsigned long long u64;
typedef short  bf16x8 __attribute__((ext_vector_type(8)));
typedef float  f32x4  __attribute__((ext_vector_type(4)));

__device__ __forceinline__ u16 f2bf(float f) {
    __hip_bfloat16 h = __float2bfloat16(f);   // RNE
    return *(u16*)&h;
}

// ws layout: [0,32) counts[8] | [256, 262400) tok_list[8][8192]
// The first 32KB of the tok_list region is ALSO the staging area for the
// per-block gate records (512 blocks x 64B). route_kernel loads all staging
// into regs/LDS before scattering over it (scatter overlaps expert-0 segment).

// ---------------------------------------------------------------------------
// gate: 512 blocks x 256 thr; each block 16 tokens, each wave 4 tokens.
// Per token: full wave, 8 lane-groups x 8 lanes; group g computes expert g.
// No LDS staging of Wg (L1-resident), no global atomics.
// ---------------------------------------------------------------------------
__global__ __launch_bounds__(256) void gate_kernel(
    const float* __restrict__ x, const float* __restrict__ Wg,
    const float* __restrict__ bg, u32* __restrict__ stage)
{
    __shared__ int   am_s[16];
    __shared__ float mg_s[4][NE];

    const int tid  = threadIdx.x;
    const int wave = tid >> 6;
    const int lane = tid & 63;
    const int g    = lane >> 3;                 // expert this lane group computes
    const int sub  = lane & 7;

    const float* wr = Wg + g * DIN + 4 * sub;

    float bgl[NE];
    #pragma unroll
    for (int e = 0; e < NE; ++e) bgl[e] = bg[e];

    float mgacc = 0.f;                          // lane<8: partial mean-gate

    #pragma unroll 1
    for (int it = 0; it < 4; ++it) {
        const int t = blockIdx.x * 16 + wave * 4 + it;
        const float* xr = x + (size_t)t * DIN + 4 * sub;

        // k = 4*sub + 128*j + {0,32,64,96} + q  covers [0,1024) exactly
        float acc0 = 0.f, acc1 = 0.f, acc2 = 0.f, acc3 = 0.f;
        #pragma unroll
        for (int j = 0; j < 8; ++j) {
            const int k = j * 128;
            f32x4 x0 = *(const f32x4*)(xr + k);
            f32x4 w0 = *(const f32x4*)(wr + k);
            f32x4 x1 = *(const f32x4*)(xr + k + 32);
            f32x4 w1 = *(const f32x4*)(wr + k + 32);
            f32x4 x2 = *(const f32x4*)(xr + k + 64);
            f32x4 w2 = *(const f32x4*)(wr + k + 64);
            f32x4 x3 = *(const f32x4*)(xr + k + 96);
            f32x4 w3 = *(const f32x4*)(wr + k + 96);
            #pragma unroll
            for (int q = 0; q < 4; ++q) {
                acc0 = fmaf(w0[q], x0[q], acc0);
                acc1 = fmaf(w1[q], x1[q], acc1);
                acc2 = fmaf(w2[q], x2[q], acc2);
                acc3 = fmaf(w3[q], x3[q], acc3);
            }
        }
        float acc = (acc0 + acc1) + (acc2 + acc3);

        // reduce across the 8 lanes of this expert group
        acc += __shfl_xor(acc, 1, 64);
        acc += __shfl_xor(acc, 2, 64);
        acc += __shfl_xor(acc, 4, 64);

        // every lane gathers all 8 expert logits
        float logit[NE];
        #pragma unroll
        for (int e = 0; e < NE; ++e)
            logit[e] = __shfl(acc, e * 8, 64) + bgl[e];

        // argmax, first-max wins (matches np/jnp)
        float m = logit[0]; int am = 0;
        #pragma unroll
        for (int e = 1; e < NE; ++e) if (logit[e] > m) { m = logit[e]; am = e; }

        float p[NE], s = 0.f;
        #pragma unroll
        for (int e = 0; e < NE; ++e) { p[e] = __expf(logit[e] - m); s += p[e]; }
        const float inv = 1.f / s;

        // lane<8 accumulates softmax prob of expert `lane` (static select chain)
        float psel = p[0];
        #pragma unroll
        for (int e = 1; e < NE; ++e) psel = (lane == e) ? p[e] : psel;
        if (lane < NE) mgacc += psel * inv;

        if (lane == 0) am_s[wave * 4 + it] = am;
    }

    if (lane < NE) mg_s[wave][lane] = mgacc;
    __syncthreads();

    // per-block record: words[0..1] = packed 16x4bit argmax, words[2..9] = mg
    u32* rec = stage + (size_t)blockIdx.x * 16;
    if (tid == 0) {
        u64 pack = 0;
        #pragma unroll
        for (int i = 0; i < 16; ++i) pack |= (u64)am_s[i] << (4 * i);
        *(u64*)rec = pack;
    }
    if (tid < NE) {
        float s = mg_s[0][tid] + mg_s[1][tid] + mg_s[2][tid] + mg_s[3][tid];
        rec[2 + tid] = __float_as_uint(s);
    }
}

// ---------------------------------------------------------------------------
// route: 1 block x 512 threads. Thread i owns gate-block i (16 tokens).
// Load all records -> count -> per-expert exclusive scan over blocks ->
// scatter into tok_list -> counts[], mg totals, aux. No atomics anywhere.
// ---------------------------------------------------------------------------
__global__ __launch_bounds__(512) void route_kernel(
    const u32* __restrict__ stage, int* __restrict__ counts,
    int* __restrict__ tok_list, float* __restrict__ out)
{
    __shared__ float mgl[512][NE];   // 16 KB
    __shared__ int   c[512][9];      // 18 KB (pad to 9 -> bank spread)
    __shared__ float tot_s[NE];

    const int tid  = threadIdx.x;
    const int wave = tid >> 6;       // 8 waves; wave w owns expert w
    const int lane = tid & 63;

    // load my block's record (completes before first barrier -> safe to
    // overwrite staging during scatter)
    const u64 pack = *(const u64*)(stage + (size_t)tid * 16);
    #pragma unroll
    for (int e = 0; e < NE; ++e)
        mgl[tid][e] = __uint_as_float(stage[tid * 16 + 2 + e]);

    #pragma unroll
    for (int e = 0; e < 9; ++e) c[tid][e] = 0;

    #pragma unroll
    for (int it = 0; it < 16; ++it) {
        int e3 = (int)((pack >> (4 * it)) & 7);
        c[tid][e3]++;
    }
    __syncthreads();

    // exclusive scan of c[*][e] along blocks, wave `e` handles expert e
    {
        const int e = wave;
        int carry = 0;
        #pragma unroll 1
        for (int ch = 0; ch < 8; ++ch) {
            int v = c[ch * 64 + lane][e];
            int incl = v;
            #pragma unroll
            for (int off = 1; off < 64; off <<= 1) {
                int n = __shfl_up(incl, off, 64);
                if (lane >= off) incl += n;
            }
            c[ch * 64 + lane][e] = incl - v + carry;
            carry += __shfl(incl, 63, 64);
        }
        if (lane == 0) counts[e] = carry;
    }
    __syncthreads();

    // scatter: c[i][e] now holds global base for block i / expert e
    #pragma unroll
    for (int it = 0; it < 16; ++it) {
        int e3 = (int)((pack >> (4 * it)) & 7);
        int pos = c[tid][e3]++;
        tok_list[e3 * NTOK + pos] = tid * 16 + it;
    }

    // mean-gate totals + aux (no extra kernel)
    {
        const int e = wave;
        float s = 0.f;
        #pragma unroll
        for (int ch = 0; ch < 8; ++ch) s += mgl[ch * 64 + lane][e];
        #pragma unroll
        for (int off = 32; off > 0; off >>= 1) s += __shfl_xor(s, off, 64);
        if (lane == 0) tot_s[e] = s;
    }
    __syncthreads();
    if (tid == 0) {
        float s = 0.f;
        #pragma unroll
        for (int e = 0; e < NE; ++e) {
            float m = tot_s[e] * (8.0f / 8192.0f);   // mean_gate * E
            s += m * m;
        }
        out[(size_t)NTOK * DOUT] = s * 0.125f;
    }
}

// ---------------------------------------------------------------------------
// grouped GEMM: per expert e, C[rows(e), 1024] = X[rows(e), :] @ We[e]^T + be[e]
// 128x128 tile, BK=32, 4 waves each 64x64 (4x4 of mfma 16x16x32 bf16).
// fp32 global -> cvt bf16 -> LDS staging; fp32 epilogue writes.
// (round-0 single-buffer version; dbuf variant regressed ~17us)
// ---------------------------------------------------------------------------
__global__ __launch_bounds__(256) void moe_gemm(
    const float* __restrict__ x, const float* __restrict__ We,
    const float* __restrict__ be, const int* __restrict__ counts,
    const int* __restrict__ tok_list, float* __restrict__ out)
{
    const int e   = blockIdx.z;
    const int cnt = counts[e];
    const int m0  = blockIdx.y * 128;
    if (m0 >= cnt) return;
    const int n0  = blockIdx.x * 128;

    __shared__ u16 sA[128 * 32];
    __shared__ u16 sB[128 * 32];
    __shared__ int toks[128];

    const int tid = threadIdx.x;
    if (tid < 128) {
        int gr = m0 + tid;
        toks[tid] = (gr < cnt) ? tok_list[e * NTOK + gr] : tok_list[e * NTOK];
    }
    __syncthreads();

    const int lane = tid & 63;
    const int wave = tid >> 6;
    const int wm   = (wave & 1) * 64;
    const int wn   = (wave >> 1) * 64;
    const int lrow = lane & 15;
    const int quad = lane >> 4;

    f32x4 acc[4][4];
    #pragma unroll
    for (int i = 0; i < 4; ++i)
        #pragma unroll
        for (int j = 0; j < 4; ++j) acc[i][j] = (f32x4){0.f, 0.f, 0.f, 0.f};

    const int srow  = tid >> 1;        // 0..127
    const int shalf = (tid & 1) * 16;  // 0 / 16 elems

    const float* xrow = x  + (size_t)toks[srow] * DIN + shalf;
    const float* brow = We + ((size_t)e << 20) + ((size_t)(n0 + srow) << 10) + shalf;

    #pragma unroll 1
    for (int k0 = 0; k0 < DIN; k0 += 32) {
        f32x4 a[4], b[4];
        #pragma unroll
        for (int q = 0; q < 4; ++q) {
            a[q] = *(const f32x4*)(xrow + k0 + 4 * q);
            b[q] = *(const f32x4*)(brow + k0 + 4 * q);
        }
        union { u16 h[16]; uint4 u[2]; } pa, pb;
        #pragma unroll
        for (int q = 0; q < 4; ++q)
            #pragma unroll
            for (int j = 0; j < 4; ++j) {
                pa.h[q * 4 + j] = f2bf(a[q][j]);
                pb.h[q * 4 + j] = f2bf(b[q][j]);
            }
        *(uint4*)&sA[srow * 32 + shalf]     = pa.u[0];
        *(uint4*)&sA[srow * 32 + shalf + 8] = pa.u[1];
        *(uint4*)&sB[srow * 32 + shalf]     = pb.u[0];
        *(uint4*)&sB[srow * 32 + shalf + 8] = pb.u[1];
        __syncthreads();

        bf16x8 af[4], bfr[4];
        #pragma unroll
        for (int i = 0; i < 4; ++i)
            af[i] = *(const bf16x8*)&sA[(wm + i * 16 + lrow) * 32 + quad * 8];
        #pragma unroll
        for (int j = 0; j < 4; ++j)
            bfr[j] = *(const bf16x8*)&sB[(wn + j * 16 + lrow) * 32 + quad * 8];
        #pragma unroll
        for (int i = 0; i < 4; ++i)
            #pragma unroll
            for (int j = 0; j < 4; ++j)
                acc[i][j] = __builtin_amdgcn_mfma_f32_16x16x32_bf16(
                    af[i], bfr[j], acc[i][j], 0, 0, 0);
        __syncthreads();
    }

    // epilogue: D lane map col=lane&15 (N), row=quad*4+r (M); fp32 stores
    #pragma unroll
    for (int j = 0; j < 4; ++j) {
        const int col = n0 + wn + j * 16 + lrow;
        const float bev = be[e * DOUT + col];
        #pragma unroll
        for (int i = 0; i < 4; ++i) {
            #pragma unroll
            for (int r = 0; r < 4; ++r) {
                const int rl = wm + i * 16 + quad * 4 + r;
                if (m0 + rl < cnt) {
                    const int tok = toks[rl];
                    out[((size_t)tok << 10) + col] = acc[i][j][r] + bev;
                }
            }
        }
    }
}

extern "C" void kernel_launch(void* const* d_in, const int* in_sizes, int n_in,
                              void* d_out, int out_size, void* d_ws, size_t ws_size,
                              hipStream_t stream) {
    const float* x  = (const float*)d_in[0];
    const float* We = (const float*)d_in[1];
    const float* be = (const float*)d_in[2];
    const float* Wg = (const float*)d_in[3];
    const float* bg = (const float*)d_in[4];
    float* out = (float*)d_out;

    int* counts   = (int*)d_ws;
    int* tok_list = (int*)((char*)d_ws + 256);
    u32* stage    = (u32*)((char*)d_ws + 256);   // staging head of tok_list region

    gate_kernel<<<512, 256, 0, stream>>>(x, Wg, bg, stage);
    route_kernel<<<1, 512, 0, stream>>>(stage, counts, tok_list, out);
    moe_gemm<<<dim3(8, 64, 8), 256, 0, stream>>>(x, We, be, counts, tok_list, out);
}